// Round 2
// 256.645 us; speedup vs baseline: 1.0223x; 1.0223x over previous
//
#include <hip/hip_runtime.h>
#include <math.h>

#define D_DIM 512

typedef short short8v __attribute__((ext_vector_type(8)));
typedef unsigned short ushort8v __attribute__((ext_vector_type(8)));
typedef unsigned short ushort4v __attribute__((ext_vector_type(4)));
typedef float f32x16 __attribute__((ext_vector_type(16)));

__device__ inline unsigned short f2bf(float f) {
    union { float f; unsigned int u; } a; a.f = f;
    unsigned int u = a.u;
    unsigned int r = (u + 0x7fffu + ((u >> 16) & 1u)) >> 16;  // RNE
    return (unsigned short)r;
}

// fast tanh: 1 - 2/(e^{2y}+1); saturates correctly at +-1
__device__ inline float fast_tanh(float y) {
    float e2 = __expf(2.f * y);
    return 1.f - __fdividef(2.f, e2 + 1.f);
}

// async 16B global -> LDS (HW scatters lane i at wave-uniform base + i*16)
#define ASYNC_CP16(gp, lp) \
    __builtin_amdgcn_global_load_lds( \
        (const __attribute__((address_space(1))) void*)(gp), \
        (__attribute__((address_space(3))) void*)(lp), 16, 0, 0)

// ---------------------------------------------------------------------------
// wt: W[k][e] fp32 -> Wb2 stage-tiled bf16.  (round-0 verified layout)
// Wb2 ushort idx: stage s (32 k) * 16384 + chunk(((nt*2+ks)*2+half)*32+nl)*8+j
// holding W[k=32s+16ks+8half+j][e=32nt+nl].
// ---------------------------------------------------------------------------
__global__ __launch_bounds__(1024) void wt_kernel(const float* __restrict__ W,
                                                  unsigned short* __restrict__ Wb2) {
    __shared__ __align__(16) unsigned short lbuf[16384];   // 32 KiB
    const int s = blockIdx.x;          // 0..15
    const int tid = threadIdx.x;
    #pragma unroll
    for (int i = 0; i < 4; ++i) {
        int flat = tid + i * 1024;     // 0..4095 float4-chunks of this stage
        int kr = flat >> 7;            // 0..31
        int e4 = (flat & 127) * 4;
        float4 v = *(const float4*)(W + (size_t)(s * 32 + kr) * D_DIM + e4);
        int ks = kr >> 4, half = (kr >> 3) & 1, j = kr & 7;
        float vv[4] = {v.x, v.y, v.z, v.w};
        #pragma unroll
        for (int q = 0; q < 4; ++q) {
            int e = e4 + q, nt = e >> 5, nl = e & 31;
            lbuf[(((nt * 2 + ks) * 2 + half) * 32 + nl) * 8 + j] = f2bf(vv[q]);
        }
    }
    __syncthreads();
    #pragma unroll
    for (int i = 0; i < 2; ++i) {
        int c = tid + i * 1024;        // 0..2047 8-ushort chunks
        *(ushort8v*)(Wb2 + (size_t)s * 16384 + c * 8) = *(const ushort8v*)&lbuf[c * 8];
    }
}

// ---------------------------------------------------------------------------
// MFMA GEMM + fused tanh/dot-u epilogue.
// Tile 64 rows x 512 cols; 512 thr = 8 waves; each wave owns 64x64
// (cols wave*64..+63) as 2x2 32x32 tiles -> acc[2][2] = 64 regs.
// LDS: W dbuf 64K + x dbuf 10K + rowpart 2K = 76K -> 2 blocks/CU
// (4 waves/SIMD): one block's MFMA hides the other's vmcnt(0) drain.
// K in 16 stages of 32; W via async global_load_lds; x fp32->bf16 in-reg.
// One barrier per stage.
// ---------------------------------------------------------------------------
constexpr int XLDE = 40;   // x LDS row stride (ushorts), 80B: 16B-aligned

__global__ __launch_bounds__(512, 4) void gemm_ait_mfma(
    const float* __restrict__ x, const unsigned short* __restrict__ Wb2,
    const float* __restrict__ bias, const float* __restrict__ u,
    float* __restrict__ ait)
{
    __shared__ __align__(16) unsigned short wsh[2][16384];    // 64 KiB
    __shared__ __align__(16) unsigned short xs[2][64 * XLDE]; // 10 KiB
    __shared__ float rowpart[8][64];                          // 2 KiB

    const int tid  = threadIdx.x;
    const int wave = tid >> 6;        // 0..7 : cols wave*64..+63
    const int lane = tid & 63;
    const int half = lane >> 5;
    const int nl   = lane & 31;
    const int m0   = blockIdx.x * 64;

    f32x16 acc[2][2];
    #pragma unroll
    for (int mi = 0; mi < 2; ++mi)
        #pragma unroll
        for (int ni = 0; ni < 2; ++ni)
            #pragma unroll
            for (int r = 0; r < 16; ++r) acc[mi][ni][r] = 0.f;

    const int xr  = tid >> 3;    // 0..63 (x row)
    const int xc4 = tid & 7;     // 0..7  (4-elem k-chunk)
    const float* xbase = x + (size_t)(m0 + xr) * D_DIM + xc4 * 4;

    // prologue: DMA W stage 0 (4 x 16B per thread), load x stage 0
    #pragma unroll
    for (int i = 0; i < 4; ++i)
        ASYNC_CP16(Wb2 + tid * 8 + i * 4096, &wsh[0][tid * 8 + i * 4096]);
    float4 px = *(const float4*)(xbase);

    for (int s = 0; s < 16; ++s) {
        const int pb = s & 1;
        {
            ushort4v pk;
            pk[0] = f2bf(px.x); pk[1] = f2bf(px.y);
            pk[2] = f2bf(px.z); pk[3] = f2bf(px.w);
            *(ushort4v*)&xs[pb][xr * XLDE + xc4 * 4] = pk;
        }
        __syncthreads();   // xs[pb] + wsh[pb] ready

        if (s + 1 < 16) {
            const unsigned short* wsrc = Wb2 + (size_t)(s + 1) * 16384;
            #pragma unroll
            for (int i = 0; i < 4; ++i)
                ASYNC_CP16(wsrc + tid * 8 + i * 4096, &wsh[1 - pb][tid * 8 + i * 4096]);
            px = *(const float4*)(xbase + (s + 1) * 32);
        }

        #pragma unroll
        for (int ks = 0; ks < 2; ++ks) {
            short8v af[2], bfr[2];
            #pragma unroll
            for (int mi = 0; mi < 2; ++mi)
                af[mi] = *(const short8v*)&xs[pb][(mi * 32 + nl) * XLDE + ks * 16 + half * 8];
            #pragma unroll
            for (int ni = 0; ni < 2; ++ni)
                bfr[ni] = *(const short8v*)&wsh[pb][(((wave * 2 + ni) * 2 + ks) * 2 + half) * 256 + nl * 8];
            #pragma unroll
            for (int mi = 0; mi < 2; ++mi)
                #pragma unroll
                for (int ni = 0; ni < 2; ++ni)
                    acc[mi][ni] = __builtin_amdgcn_mfma_f32_32x32x16_bf16(
                        af[mi], bfr[ni], acc[mi][ni], 0, 0, 0);
        }
        // next iter writes the other buffers; its barrier orders everything
    }

    // epilogue: ait[m] = sum_e tanh(C[m][e]+bias[e]) * u[e]
    // C/D layout: col = lane&31, row = (reg&3) + 8*(reg>>2) + 4*(lane>>5)
    float rowsum[2][16];
    #pragma unroll
    for (int mi = 0; mi < 2; ++mi)
        #pragma unroll
        for (int r = 0; r < 16; ++r) rowsum[mi][r] = 0.f;

    #pragma unroll
    for (int mi = 0; mi < 2; ++mi) {
        #pragma unroll
        for (int ni = 0; ni < 2; ++ni) {
            int col = wave * 64 + ni * 32 + nl;
            float be = bias[col], ue = u[col];
            #pragma unroll
            for (int r = 0; r < 16; ++r)
                rowsum[mi][r] += fast_tanh(acc[mi][ni][r] + be) * ue;
        }
    }
    #pragma unroll
    for (int mi = 0; mi < 2; ++mi)
        #pragma unroll
        for (int r = 0; r < 16; ++r) {
            float v = rowsum[mi][r];
            v += __shfl_xor(v, 1, 64);
            v += __shfl_xor(v, 2, 64);
            v += __shfl_xor(v, 4, 64);
            v += __shfl_xor(v, 8, 64);
            v += __shfl_xor(v, 16, 64);
            rowsum[mi][r] = v;
        }
    if (nl == 0) {
        #pragma unroll
        for (int mi = 0; mi < 2; ++mi)
            #pragma unroll
            for (int r = 0; r < 16; ++r) {
                int row = mi * 32 + (r & 3) + 8 * (r >> 2) + 4 * half;
                rowpart[wave][row] = rowsum[mi][r];
            }
    }
    __syncthreads();
    if (tid < 64) {
        float s = 0.f;
        #pragma unroll
        for (int w = 0; w < 8; ++w) s += rowpart[w][tid];
        ait[m0 + tid] = s;
    }
}

// ---- fp32 fallback GEMM (only if ws < 768 KiB — never observed) ----
__global__ __launch_bounds__(256) void gemm_ait_f32(
    const float* __restrict__ x, const float* __restrict__ W,
    const float* __restrict__ bias, const float* __restrict__ u,
    float* __restrict__ ait)
{
    __shared__ float xsf[64][68];
    __shared__ float wshf[64][132];
    const int tid = threadIdx.x;
    const int tx = tid & 15, ty = tid >> 4;
    const int m0 = blockIdx.x * 64;
    float rowsum[4] = {0.f, 0.f, 0.f, 0.f};
    for (int e0 = 0; e0 < D_DIM; e0 += 128) {
        float acc[4][8];
        #pragma unroll
        for (int i = 0; i < 4; ++i)
            #pragma unroll
            for (int j = 0; j < 8; ++j) acc[i][j] = 0.f;
        for (int kc = 0; kc < D_DIM; kc += 64) {
            #pragma unroll
            for (int i = 0; i < 4; ++i) {
                int idx = tid + i * 256;
                int r = idx >> 4, c = (idx & 15) * 4;
                *(float4*)&xsf[r][c] = *(const float4*)(x + (size_t)(m0 + r) * D_DIM + kc + c);
            }
            #pragma unroll
            for (int i = 0; i < 8; ++i) {
                int idx = tid + i * 256;
                int r = idx >> 5, c = (idx & 31) * 4;
                *(float4*)&wshf[r][c] = *(const float4*)(W + (size_t)(kc + r) * D_DIM + e0 + c);
            }
            __syncthreads();
            #pragma unroll 4
            for (int k = 0; k < 64; ++k) {
                float xv[4];
                #pragma unroll
                for (int i = 0; i < 4; ++i) xv[i] = xsf[ty * 4 + i][k];
                float4 w0 = *(const float4*)&wshf[k][tx * 8];
                float4 w1 = *(const float4*)&wshf[k][tx * 8 + 4];
                #pragma unroll
                for (int i = 0; i < 4; ++i) {
                    acc[i][0] += xv[i] * w0.x; acc[i][1] += xv[i] * w0.y;
                    acc[i][2] += xv[i] * w0.z; acc[i][3] += xv[i] * w0.w;
                    acc[i][4] += xv[i] * w1.x; acc[i][5] += xv[i] * w1.y;
                    acc[i][6] += xv[i] * w1.z; acc[i][7] += xv[i] * w1.w;
                }
            }
            __syncthreads();
        }
        #pragma unroll
        for (int j = 0; j < 8; ++j) {
            int e = e0 + tx * 8 + j;
            float be = bias[e], ue = u[e];
            #pragma unroll
            for (int i = 0; i < 4; ++i) rowsum[i] += tanhf(acc[i][j] + be) * ue;
        }
    }
    float* red = &xsf[0][0];
    #pragma unroll
    for (int i = 0; i < 4; ++i) red[(ty * 4 + i) * 16 + tx] = rowsum[i];
    __syncthreads();
    if (tid < 64) {
        float s = 0.f;
        #pragma unroll
        for (int j = 0; j < 16; ++j) s += red[tid * 16 + j];
        ait[m0 + tid] = s;
    }
}

// ---- softmax over T (in-place, plain exp + eps) ----
__global__ __launch_bounds__(256) void softmax_kernel(float* __restrict__ ait, int T)
{
    const int b = blockIdx.x;
    float* p = ait + (size_t)b * T;
    const int tid = threadIdx.x;
    float ev[8];
    float local = 0.f;
    #pragma unroll
    for (int i = 0; i < 8; ++i) {
        ev[i] = expf(p[tid + i * 256]);
        local += ev[i];
    }
    #pragma unroll
    for (int off = 32; off > 0; off >>= 1)
        local += __shfl_down(local, off, 64);
    __shared__ float wsum[4];
    const int wv = tid >> 6, lane = tid & 63;
    if (lane == 0) wsum[wv] = local;
    __syncthreads();
    float total = wsum[0] + wsum[1] + wsum[2] + wsum[3];
    float inv = 1.0f / (total + 1e-7f);
    #pragma unroll
    for (int i = 0; i < 8; ++i) p[tid + i * 256] = ev[i] * inv;
}

// ---- pooling: 256-t chunk per block (8/batch, 256 blocks), 4 t-streams ----
__global__ __launch_bounds__(512) void pool_partial_kernel(
    const float* __restrict__ x, const float* __restrict__ a,
    float* __restrict__ partial, int T)
{
    const int chunks = T >> 8;               // 8
    const int b = blockIdx.x / chunks;
    const int c = blockIdx.x % chunks;
    const int tid = threadIdx.x;
    const int th = tid >> 7;                 // 4 t-streams
    const int d = (tid & 127) * 4;

    const float* xp = x + ((size_t)b * T + c * 256) * D_DIM + d;
    const float* ap = a + (size_t)b * T + c * 256;

    float4 acc = {0.f, 0.f, 0.f, 0.f};
    #pragma unroll 8
    for (int t = th; t < 256; t += 4) {      // 64 iters/stream
        float s = ap[t];
        float4 xv = *(const float4*)(xp + (size_t)t * D_DIM);
        acc.x += xv.x * s; acc.y += xv.y * s;
        acc.z += xv.z * s; acc.w += xv.w * s;
    }
    __shared__ float4 tmp[3][128];
    if (th > 0) tmp[th - 1][tid & 127] = acc;
    __syncthreads();
    if (th == 0) {
        float4 o0 = tmp[0][tid], o1 = tmp[1][tid], o2 = tmp[2][tid];
        acc.x += o0.x + o1.x + o2.x; acc.y += o0.y + o1.y + o2.y;
        acc.z += o0.z + o1.z + o2.z; acc.w += o0.w + o1.w + o2.w;
        *(float4*)(partial + (size_t)blockIdx.x * D_DIM + tid * 4) = acc;
    }
}

__global__ __launch_bounds__(256) void pool_reduce_kernel(
    const float* __restrict__ partial, float* __restrict__ out, int chunks)
{
    const int b = blockIdx.x;
    const int tid = threadIdx.x;
    const int d = tid * 2;
    float2 acc = {0.f, 0.f};
    for (int c = 0; c < chunks; ++c) {
        float2 v = *(const float2*)(partial + ((size_t)b * chunks + c) * D_DIM + d);
        acc.x += v.x; acc.y += v.y;
    }
    *(float2*)(out + (size_t)b * D_DIM + d) = acc;
}

// ---- fallback pool (tiny-ws path only) ----
__global__ __launch_bounds__(256) void pool_atomic_kernel(
    const float* __restrict__ x, const float* __restrict__ a,
    float* __restrict__ out, int T)
{
    const int chunks = T >> 8;
    const int b = blockIdx.x / chunks;
    const int c = blockIdx.x % chunks;
    const int tid = threadIdx.x;
    const int th = tid >> 7;
    const int d = (tid & 127) * 4;
    const float* xp = x + ((size_t)b * T + c * 256) * D_DIM + d;
    const float* ap = a + (size_t)b * T + c * 256;
    float4 acc = {0.f, 0.f, 0.f, 0.f};
    #pragma unroll 8
    for (int t = th; t < 256; t += 2) {
        float s = ap[t];
        float4 xv = *(const float4*)(xp + (size_t)t * D_DIM);
        acc.x += xv.x * s; acc.y += xv.y * s;
        acc.z += xv.z * s; acc.w += xv.w * s;
    }
    __shared__ float4 tmp[128];
    if (th == 1) tmp[tid & 127] = acc;
    __syncthreads();
    if (th == 0) {
        float4 o = tmp[tid];
        float* op = out + (size_t)b * D_DIM + tid * 4;
        atomicAdd(op + 0, acc.x + o.x);
        atomicAdd(op + 1, acc.y + o.y);
        atomicAdd(op + 2, acc.z + o.z);
        atomicAdd(op + 3, acc.w + o.w);
    }
}

extern "C" void kernel_launch(void* const* d_in, const int* in_sizes, int n_in,
                              void* d_out, int out_size, void* d_ws, size_t ws_size,
                              hipStream_t stream)
{
    const float* x    = (const float*)d_in[0];
    const float* W    = (const float*)d_in[1];
    const float* bias = (const float*)d_in[2];
    const float* u    = (const float*)d_in[3];
    float* out = (float*)d_out;

    const int Dd = in_sizes[2];          // 512
    const int M  = in_sizes[0] / Dd;     // 65536
    const int B  = out_size / Dd;        // 32
    const int T  = M / B;                // 2048
    const int chunks = T >> 8;           // 8

    const size_t wb_bytes  = (size_t)Dd * Dd * sizeof(unsigned short);   // 512 KiB
    const size_t ait_bytes = (size_t)M * sizeof(float);                  // 256 KiB

    if (ws_size >= wb_bytes + ait_bytes) {
        // [0, 512K): Wb2 during GEMM, then reused as pool partials.
        // [512K, 768K): ait (softmax in-place -> a).
        unsigned short* Wb2 = (unsigned short*)d_ws;
        float* ait     = (float*)((char*)d_ws + wb_bytes);
        float* partial = (float*)d_ws;    // reuse after gemm completes

        wt_kernel<<<dim3(16), dim3(1024), 0, stream>>>(W, Wb2);
        gemm_ait_mfma<<<dim3(M / 64), dim3(512), 0, stream>>>(x, Wb2, bias, u, ait);
        softmax_kernel<<<dim3(B), dim3(256), 0, stream>>>(ait, T);
        pool_partial_kernel<<<dim3(B * chunks), dim3(512), 0, stream>>>(x, ait, partial, T);
        pool_reduce_kernel<<<dim3(B), dim3(256), 0, stream>>>(partial, out, chunks);
    } else {
        float* ait = (float*)d_ws;
        gemm_ait_f32<<<dim3(M / 64), dim3(256), 0, stream>>>(x, W, bias, u, ait);
        softmax_kernel<<<dim3(B), dim3(256), 0, stream>>>(ait, T);
        hipMemsetAsync(d_out, 0, (size_t)out_size * sizeof(float), stream);
        pool_atomic_kernel<<<dim3(B * chunks), dim3(256), 0, stream>>>(x, ait, out, T);
    }
}

// Round 3
// 242.104 us; speedup vs baseline: 1.0837x; 1.0601x over previous
//
#include <hip/hip_runtime.h>
#include <math.h>

#define D_DIM 512

typedef short short8v __attribute__((ext_vector_type(8)));
typedef unsigned short ushort8v __attribute__((ext_vector_type(8)));
typedef unsigned short ushort4v __attribute__((ext_vector_type(4)));
typedef float f32x16 __attribute__((ext_vector_type(16)));

__device__ inline unsigned short f2bf(float f) {
    union { float f; unsigned int u; } a; a.f = f;
    unsigned int u = a.u;
    unsigned int r = (u + 0x7fffu + ((u >> 16) & 1u)) >> 16;  // RNE
    return (unsigned short)r;
}

// fast tanh: 1 - 2/(e^{2y}+1); saturates correctly at +-1
__device__ inline float fast_tanh(float y) {
    float e2 = __expf(2.f * y);
    return 1.f - __fdividef(2.f, e2 + 1.f);
}

// async 16B global -> LDS (HW scatters lane i at wave-uniform base + i*16)
#define ASYNC_CP16(gp, lp) \
    __builtin_amdgcn_global_load_lds( \
        (const __attribute__((address_space(1))) void*)(gp), \
        (__attribute__((address_space(3))) void*)(lp), 16, 0, 0)

// ---------------------------------------------------------------------------
// wt: W[k][e] fp32 -> Wb2 stage-tiled bf16 (round-0 verified layout).
// Wb2 ushort idx: stage s (32 k) * 16384 + chunk(((nt*2+ks)*2+half)*32+nl)*8+j
// holding W[k=32s+16ks+8half+j][e=32nt+nl].
// Block 0 additionally zeroes the numer/denom accumulators (16416 floats).
// ---------------------------------------------------------------------------
__global__ __launch_bounds__(1024) void wt_kernel(const float* __restrict__ W,
                                                  unsigned short* __restrict__ Wb2,
                                                  float* __restrict__ zero_base,
                                                  int zero_count) {
    __shared__ __align__(16) unsigned short lbuf[16384];   // 32 KiB
    const int s = blockIdx.x;          // 0..15
    const int tid = threadIdx.x;
    if (s == 0) {
        for (int i = tid; i < zero_count; i += 1024) zero_base[i] = 0.f;
    }
    #pragma unroll
    for (int i = 0; i < 4; ++i) {
        int flat = tid + i * 1024;     // 0..4095 float4-chunks of this stage
        int kr = flat >> 7;            // 0..31
        int e4 = (flat & 127) * 4;
        float4 v = *(const float4*)(W + (size_t)(s * 32 + kr) * D_DIM + e4);
        int ks = kr >> 4, half = (kr >> 3) & 1, j = kr & 7;
        float vv[4] = {v.x, v.y, v.z, v.w};
        #pragma unroll
        for (int q = 0; q < 4; ++q) {
            int e = e4 + q, nt = e >> 5, nl = e & 31;
            lbuf[(((nt * 2 + ks) * 2 + half) * 32 + nl) * 8 + j] = f2bf(vv[q]);
        }
    }
    __syncthreads();
    #pragma unroll
    for (int i = 0; i < 2; ++i) {
        int c = tid + i * 1024;        // 0..2047 8-ushort chunks
        *(ushort8v*)(Wb2 + (size_t)s * 16384 + c * 8) = *(const ushort8v*)&lbuf[c * 8];
    }
}

// ---------------------------------------------------------------------------
// Fused MFMA GEMM + tanh/dot-u + exp + weighted-pool epilogue.
// Tile 64 rows x 512 cols; 512 thr = 8 waves; wave owns 64x64 -> acc[2][2].
// LDS: W dbuf 64K + x dbuf 10K + rowpart 2K = 76K -> 2 blocks/CU.
// After the K loop: ait[64] -> e = exp(ait) (unnormalized), block-partial
// denominator via 1 atomicAdd, then weighted row-sum of the block's own
// (L2/LLC-hot) 64x512 x tile into numer[b][*] via 512 atomicAdds.
// out = numer/(denom+eps) computed by a trivial final kernel.
// wsh/xs are reused as epilogue scratch behind barriers.
// ---------------------------------------------------------------------------
constexpr int XLDE = 40;   // x LDS row stride (ushorts), 80B: 16B-aligned

__global__ __launch_bounds__(512, 4) void gemm_ait_fused(
    const float* __restrict__ x, const unsigned short* __restrict__ Wb2,
    const float* __restrict__ bias, const float* __restrict__ u,
    float* __restrict__ numer, float* __restrict__ denom, int T)
{
    __shared__ __align__(16) unsigned short wsh[2][16384];    // 64 KiB
    __shared__ __align__(16) unsigned short xs[2][64 * XLDE]; // 10 KiB
    __shared__ float rowpart[8][64];                          // 2 KiB

    const int tid  = threadIdx.x;
    const int wave = tid >> 6;        // 0..7 : cols wave*64..+63
    const int lane = tid & 63;
    const int half = lane >> 5;
    const int nl   = lane & 31;
    const int m0   = blockIdx.x * 64;

    f32x16 acc[2][2];
    #pragma unroll
    for (int mi = 0; mi < 2; ++mi)
        #pragma unroll
        for (int ni = 0; ni < 2; ++ni)
            #pragma unroll
            for (int r = 0; r < 16; ++r) acc[mi][ni][r] = 0.f;

    const int xr  = tid >> 3;    // 0..63 (x row)
    const int xc4 = tid & 7;     // 0..7  (4-elem k-chunk)
    const float* xbase = x + (size_t)(m0 + xr) * D_DIM + xc4 * 4;

    // prologue: DMA W stage 0 (4 x 16B per thread), load x stage 0
    #pragma unroll
    for (int i = 0; i < 4; ++i)
        ASYNC_CP16(Wb2 + tid * 8 + i * 4096, &wsh[0][tid * 8 + i * 4096]);
    float4 px = *(const float4*)(xbase);

    for (int s = 0; s < 16; ++s) {
        const int pb = s & 1;
        {
            ushort4v pk;
            pk[0] = f2bf(px.x); pk[1] = f2bf(px.y);
            pk[2] = f2bf(px.z); pk[3] = f2bf(px.w);
            *(ushort4v*)&xs[pb][xr * XLDE + xc4 * 4] = pk;
        }
        __syncthreads();   // xs[pb] + wsh[pb] ready

        if (s + 1 < 16) {
            const unsigned short* wsrc = Wb2 + (size_t)(s + 1) * 16384;
            #pragma unroll
            for (int i = 0; i < 4; ++i)
                ASYNC_CP16(wsrc + tid * 8 + i * 4096, &wsh[1 - pb][tid * 8 + i * 4096]);
            px = *(const float4*)(xbase + (s + 1) * 32);
        }

        #pragma unroll
        for (int ks = 0; ks < 2; ++ks) {
            short8v af[2], bfr[2];
            #pragma unroll
            for (int mi = 0; mi < 2; ++mi)
                af[mi] = *(const short8v*)&xs[pb][(mi * 32 + nl) * XLDE + ks * 16 + half * 8];
            #pragma unroll
            for (int ni = 0; ni < 2; ++ni)
                bfr[ni] = *(const short8v*)&wsh[pb][(((wave * 2 + ni) * 2 + ks) * 2 + half) * 256 + nl * 8];
            #pragma unroll
            for (int mi = 0; mi < 2; ++mi)
                #pragma unroll
                for (int ni = 0; ni < 2; ++ni)
                    acc[mi][ni] = __builtin_amdgcn_mfma_f32_32x32x16_bf16(
                        af[mi], bfr[ni], acc[mi][ni], 0, 0, 0);
        }
        // next iter writes the other buffers; its barrier orders everything
    }

    // ---- epilogue 1: ait[m] = sum_e tanh(C[m][e]+bias[e]) * u[e] ----
    // C/D layout: col = lane&31, row = (reg&3) + 8*(reg>>2) + 4*(lane>>5)
    float rowsum[2][16];
    #pragma unroll
    for (int mi = 0; mi < 2; ++mi)
        #pragma unroll
        for (int r = 0; r < 16; ++r) rowsum[mi][r] = 0.f;

    #pragma unroll
    for (int mi = 0; mi < 2; ++mi) {
        #pragma unroll
        for (int ni = 0; ni < 2; ++ni) {
            int col = wave * 64 + ni * 32 + nl;
            float be = bias[col], ue = u[col];
            #pragma unroll
            for (int r = 0; r < 16; ++r)
                rowsum[mi][r] += fast_tanh(acc[mi][ni][r] + be) * ue;
        }
    }
    #pragma unroll
    for (int mi = 0; mi < 2; ++mi)
        #pragma unroll
        for (int r = 0; r < 16; ++r) {
            float v = rowsum[mi][r];
            v += __shfl_xor(v, 1, 64);
            v += __shfl_xor(v, 2, 64);
            v += __shfl_xor(v, 4, 64);
            v += __shfl_xor(v, 8, 64);
            v += __shfl_xor(v, 16, 64);
            rowsum[mi][r] = v;
        }
    if (nl == 0) {
        #pragma unroll
        for (int mi = 0; mi < 2; ++mi)
            #pragma unroll
            for (int r = 0; r < 16; ++r) {
                int row = mi * 32 + (r & 3) + 8 * (r >> 2) + 4 * half;
                rowpart[wave][row] = rowsum[mi][r];
            }
    }
    __syncthreads();   // rowpart complete; wsh/xs dead -> reusable as scratch

    // ---- epilogue 2: e = exp(ait), denom atomic ----
    const int b = m0 / T;                       // batch of this 64-row tile
    float* evals = (float*)&xs[0][0];           // 64 floats, reused LDS
    if (tid < 64) {
        float s = 0.f;
        #pragma unroll
        for (int w = 0; w < 8; ++w) s += rowpart[w][tid];
        float e = __expf(s);
        evals[tid] = e;
        float t = e;
        t += __shfl_xor(t, 1, 64);
        t += __shfl_xor(t, 2, 64);
        t += __shfl_xor(t, 4, 64);
        t += __shfl_xor(t, 8, 64);
        t += __shfl_xor(t, 16, 64);
        t += __shfl_xor(t, 32, 64);
        if (tid == 0) atomicAdd(denom + b, t);
    }
    __syncthreads();   // evals ready

    // ---- epilogue 3: numer[b][d] += sum_r e[r] * x[m0+r][d] ----
    // 4 row-groups x 128 d4-threads; x tile is L2/LLC-hot (just streamed).
    const int dg = tid >> 7;                    // 0..3
    const int d4 = (tid & 127) << 2;            // 0..508
    const float* xp = x + (size_t)m0 * D_DIM + d4;
    float4 pacc = {0.f, 0.f, 0.f, 0.f};
    #pragma unroll 4
    for (int r = dg; r < 64; r += 4) {
        float e = evals[r];
        float4 xv = *(const float4*)(xp + (size_t)r * D_DIM);
        pacc.x += e * xv.x; pacc.y += e * xv.y;
        pacc.z += e * xv.z; pacc.w += e * xv.w;
    }
    float4* ptmp = (float4*)&wsh[0][0];         // 3*128 float4, reused LDS
    if (dg > 0) ptmp[(dg - 1) * 128 + (tid & 127)] = pacc;
    __syncthreads();
    if (dg == 0) {
        float4 o0 = ptmp[tid], o1 = ptmp[128 + tid], o2 = ptmp[256 + tid];
        float* np = numer + (size_t)b * D_DIM + d4;
        atomicAdd(np + 0, pacc.x + o0.x + o1.x + o2.x);
        atomicAdd(np + 1, pacc.y + o0.y + o1.y + o2.y);
        atomicAdd(np + 2, pacc.z + o0.z + o1.z + o2.z);
        atomicAdd(np + 3, pacc.w + o0.w + o1.w + o2.w);
    }
}

// ---- final divide: out[b][d] = numer[b][d] / (denom[b] + eps) ----
__global__ __launch_bounds__(128) void out_div_kernel(
    const float* __restrict__ numer, const float* __restrict__ denom,
    float* __restrict__ out)
{
    const int b = blockIdx.x;
    const int tid = threadIdx.x;
    float inv = 1.0f / (denom[b] + 1e-7f);
    float4 v = *(const float4*)(numer + (size_t)b * D_DIM + tid * 4);
    v.x *= inv; v.y *= inv; v.z *= inv; v.w *= inv;
    *(float4*)(out + (size_t)b * D_DIM + tid * 4) = v;
}

// ---- fp32 fallback GEMM (only if ws < 768 KiB — never observed) ----
__global__ __launch_bounds__(256) void gemm_ait_f32(
    const float* __restrict__ x, const float* __restrict__ W,
    const float* __restrict__ bias, const float* __restrict__ u,
    float* __restrict__ ait)
{
    __shared__ float xsf[64][68];
    __shared__ float wshf[64][132];
    const int tid = threadIdx.x;
    const int tx = tid & 15, ty = tid >> 4;
    const int m0 = blockIdx.x * 64;
    float rowsum[4] = {0.f, 0.f, 0.f, 0.f};
    for (int e0 = 0; e0 < D_DIM; e0 += 128) {
        float acc[4][8];
        #pragma unroll
        for (int i = 0; i < 4; ++i)
            #pragma unroll
            for (int j = 0; j < 8; ++j) acc[i][j] = 0.f;
        for (int kc = 0; kc < D_DIM; kc += 64) {
            #pragma unroll
            for (int i = 0; i < 4; ++i) {
                int idx = tid + i * 256;
                int r = idx >> 4, c = (idx & 15) * 4;
                *(float4*)&xsf[r][c] = *(const float4*)(x + (size_t)(m0 + r) * D_DIM + kc + c);
            }
            #pragma unroll
            for (int i = 0; i < 8; ++i) {
                int idx = tid + i * 256;
                int r = idx >> 5, c = (idx & 31) * 4;
                *(float4*)&wshf[r][c] = *(const float4*)(W + (size_t)(kc + r) * D_DIM + e0 + c);
            }
            __syncthreads();
            #pragma unroll 4
            for (int k = 0; k < 64; ++k) {
                float xv[4];
                #pragma unroll
                for (int i = 0; i < 4; ++i) xv[i] = xsf[ty * 4 + i][k];
                float4 w0 = *(const float4*)&wshf[k][tx * 8];
                float4 w1 = *(const float4*)&wshf[k][tx * 8 + 4];
                #pragma unroll
                for (int i = 0; i < 4; ++i) {
                    acc[i][0] += xv[i] * w0.x; acc[i][1] += xv[i] * w0.y;
                    acc[i][2] += xv[i] * w0.z; acc[i][3] += xv[i] * w0.w;
                    acc[i][4] += xv[i] * w1.x; acc[i][5] += xv[i] * w1.y;
                    acc[i][6] += xv[i] * w1.z; acc[i][7] += xv[i] * w1.w;
                }
            }
            __syncthreads();
        }
        #pragma unroll
        for (int j = 0; j < 8; ++j) {
            int e = e0 + tx * 8 + j;
            float be = bias[e], ue = u[e];
            #pragma unroll
            for (int i = 0; i < 4; ++i) rowsum[i] += tanhf(acc[i][j] + be) * ue;
        }
    }
    float* red = &xsf[0][0];
    #pragma unroll
    for (int i = 0; i < 4; ++i) red[(ty * 4 + i) * 16 + tx] = rowsum[i];
    __syncthreads();
    if (tid < 64) {
        float s = 0.f;
        #pragma unroll
        for (int j = 0; j < 16; ++j) s += red[tid * 16 + j];
        ait[m0 + tid] = s;
    }
}

// ---- softmax over T (fallback path) ----
__global__ __launch_bounds__(256) void softmax_kernel(float* __restrict__ ait, int T)
{
    const int b = blockIdx.x;
    float* p = ait + (size_t)b * T;
    const int tid = threadIdx.x;
    float ev[8];
    float local = 0.f;
    #pragma unroll
    for (int i = 0; i < 8; ++i) {
        ev[i] = expf(p[tid + i * 256]);
        local += ev[i];
    }
    #pragma unroll
    for (int off = 32; off > 0; off >>= 1)
        local += __shfl_down(local, off, 64);
    __shared__ float wsum[4];
    const int wv = tid >> 6, lane = tid & 63;
    if (lane == 0) wsum[wv] = local;
    __syncthreads();
    float total = wsum[0] + wsum[1] + wsum[2] + wsum[3];
    float inv = 1.0f / (total + 1e-7f);
    #pragma unroll
    for (int i = 0; i < 8; ++i) p[tid + i * 256] = ev[i] * inv;
}

// ---- fallback pool (tiny-ws path only) ----
__global__ __launch_bounds__(256) void pool_atomic_kernel(
    const float* __restrict__ x, const float* __restrict__ a,
    float* __restrict__ out, int T)
{
    const int chunks = T >> 8;
    const int b = blockIdx.x / chunks;
    const int c = blockIdx.x % chunks;
    const int tid = threadIdx.x;
    const int th = tid >> 7;
    const int d = (tid & 127) * 4;
    const float* xp = x + ((size_t)b * T + c * 256) * D_DIM + d;
    const float* ap = a + (size_t)b * T + c * 256;
    float4 acc = {0.f, 0.f, 0.f, 0.f};
    #pragma unroll 8
    for (int t = th; t < 256; t += 2) {
        float s = ap[t];
        float4 xv = *(const float4*)(xp + (size_t)t * D_DIM);
        acc.x += xv.x * s; acc.y += xv.y * s;
        acc.z += xv.z * s; acc.w += xv.w * s;
    }
    __shared__ float4 tmp[128];
    if (th == 1) tmp[tid & 127] = acc;
    __syncthreads();
    if (th == 0) {
        float4 o = tmp[tid];
        float* op = out + (size_t)b * D_DIM + tid * 4;
        atomicAdd(op + 0, acc.x + o.x);
        atomicAdd(op + 1, acc.y + o.y);
        atomicAdd(op + 2, acc.z + o.z);
        atomicAdd(op + 3, acc.w + o.w);
    }
}

extern "C" void kernel_launch(void* const* d_in, const int* in_sizes, int n_in,
                              void* d_out, int out_size, void* d_ws, size_t ws_size,
                              hipStream_t stream)
{
    const float* x    = (const float*)d_in[0];
    const float* W    = (const float*)d_in[1];
    const float* bias = (const float*)d_in[2];
    const float* u    = (const float*)d_in[3];
    float* out = (float*)d_out;

    const int Dd = in_sizes[2];          // 512
    const int M  = in_sizes[0] / Dd;     // 65536
    const int B  = out_size / Dd;        // 32
    const int T  = M / B;                // 2048
    const int chunks = T >> 8;           // 8

    const size_t wb_bytes  = (size_t)Dd * Dd * sizeof(unsigned short);   // 512 KiB
    const size_t ait_bytes = (size_t)M * sizeof(float);                  // 256 KiB

    if (ws_size >= wb_bytes + ait_bytes) {
        // [0, 512K): Wb2.  [512K, 576K): numer (B x D).  [576K, +128B): denom.
        unsigned short* Wb2 = (unsigned short*)d_ws;
        float* numer = (float*)((char*)d_ws + wb_bytes);
        float* denom = numer + (size_t)B * Dd;
        const int zero_count = B * Dd + B;   // numer + denom contiguous

        wt_kernel<<<dim3(16), dim3(1024), 0, stream>>>(W, Wb2, numer, zero_count);
        gemm_ait_fused<<<dim3(M / 64), dim3(512), 0, stream>>>(x, Wb2, bias, u,
                                                               numer, denom, T);
        out_div_kernel<<<dim3(B), dim3(128), 0, stream>>>(numer, denom, out);
    } else {
        float* ait = (float*)d_ws;
        gemm_ait_f32<<<dim3(M / 64), dim3(256), 0, stream>>>(x, W, bias, u, ait);
        softmax_kernel<<<dim3(B), dim3(256), 0, stream>>>(ait, T);
        hipMemsetAsync(d_out, 0, (size_t)out_size * sizeof(float), stream);
        pool_atomic_kernel<<<dim3(B * chunks), dim3(256), 0, stream>>>(x, ait, out, T);
    }
}

// Round 4
// 239.248 us; speedup vs baseline: 1.0966x; 1.0119x over previous
//
#include <hip/hip_runtime.h>
#include <math.h>

#define D_DIM 512

typedef short short8v __attribute__((ext_vector_type(8)));
typedef unsigned short ushort8v __attribute__((ext_vector_type(8)));
typedef float f32x16 __attribute__((ext_vector_type(16)));

__device__ inline unsigned short f2bf(float f) {
    union { float f; unsigned int u; } a; a.f = f;
    unsigned int u = a.u;
    unsigned int r = (u + 0x7fffu + ((u >> 16) & 1u)) >> 16;  // RNE
    return (unsigned short)r;
}

// fast tanh: 1 - 2/(e^{2y}+1); saturates correctly at +-1
__device__ inline float fast_tanh(float y) {
    float e2 = __expf(2.f * y);
    return 1.f - __fdividef(2.f, e2 + 1.f);
}

// async 16B global -> LDS (HW scatters lane i at wave-uniform base + i*16)
#define ASYNC_CP16(gp, lp) \
    __builtin_amdgcn_global_load_lds( \
        (const __attribute__((address_space(1))) void*)(gp), \
        (__attribute__((address_space(3))) void*)(lp), 16, 0, 0)

// 32-bit LDS offset for inline-asm DS ops
__device__ inline unsigned ldsaddr(const void* p) {
    return (unsigned)(size_t)(__attribute__((address_space(3))) const void*)p;
}

// ---------------------------------------------------------------------------
// wt: W[k][e] fp32 -> Wb2 bf16, tiled in 32 stages of 16 k.
// Wb2 ushort idx: s16*8192 + ((g*2+half)*32+nl)*8 + j
//   holding W[k = s16*16 + half*8 + j][e = g*32 + nl],  g=e>>5, nl=e&31.
// Block 0 additionally zeroes the numer/denom accumulators.
// ---------------------------------------------------------------------------
__global__ __launch_bounds__(1024) void wt_kernel(const float* __restrict__ W,
                                                  unsigned short* __restrict__ Wb2,
                                                  float* __restrict__ zero_base,
                                                  int zero_count) {
    __shared__ __align__(16) unsigned short lbuf[16384];   // 32 KiB = 2 stages
    const int s = blockIdx.x;          // 0..15 (pair of 16-k stages)
    const int tid = threadIdx.x;
    if (s == 0) {
        for (int i = tid; i < zero_count; i += 1024) zero_base[i] = 0.f;
    }
    #pragma unroll
    for (int i = 0; i < 4; ++i) {
        int flat = tid + i * 1024;     // 0..4095 float4-chunks of this stage-pair
        int kr = flat >> 7;            // 0..31
        int e4 = (flat & 127) * 4;
        float4 v = *(const float4*)(W + (size_t)(s * 32 + kr) * D_DIM + e4);
        int ks = kr >> 4, half = (kr >> 3) & 1, j = kr & 7;
        float vv[4] = {v.x, v.y, v.z, v.w};
        #pragma unroll
        for (int q = 0; q < 4; ++q) {
            int e = e4 + q, g = e >> 5, nl = e & 31;
            lbuf[ks * 8192 + ((g * 2 + half) * 32 + nl) * 8 + j] = f2bf(vv[q]);
        }
    }
    __syncthreads();
    #pragma unroll
    for (int i = 0; i < 2; ++i) {
        int c = tid + i * 1024;        // 0..2047 8-ushort chunks
        *(ushort8v*)(Wb2 + (size_t)s * 16384 + c * 8) = *(const ushort8v*)&lbuf[c * 8];
    }
}

// ---------------------------------------------------------------------------
// Fused MFMA GEMM + tanh/dot-u + exp + weighted-pool epilogue.
// Counted-vmcnt pipeline (T3+T4): K in 32 stages of 16; W DMA'd 2 stages
// ahead into a ring-4 of 16 KB LDS slots; x loaded (asm dwordx2) 2 ahead,
// bf16-packed into a ring-3. Raw s_barrier + s_waitcnt vmcnt(5): each
// iteration retires exactly {W(s), px(s+1)} while W(s+1),px(s+2),W(s+2)
// stay in flight across the barrier. asm ds_read_b128 + lgkmcnt(0) +
// sched_barrier(0) ahead of the MFMA cluster (rule #18).
// Ring safety: W slot read@s is re-DMA'd @s+2 (barrier s+1 between);
// xs slot read@s is re-written @s+2 (barrier s+1 between).
// LDS 75 KB -> 2 blocks/CU. Epilogue identical to round-3 (passing).
// ---------------------------------------------------------------------------
constexpr int XLDE = 24;   // xs row stride in ushorts (48 B: 16B-aligned, ~4-way max)

__global__ __launch_bounds__(512, 4) void gemm_ait_fused(
    const float* __restrict__ x, const unsigned short* __restrict__ Wb2,
    const float* __restrict__ bias, const float* __restrict__ u,
    float* __restrict__ numer, float* __restrict__ denom, int T)
{
    __shared__ __align__(16) unsigned short wsh[4][8192];     // 64 KiB ring-4
    __shared__ __align__(16) unsigned short xs[3][64 * XLDE]; // 9 KiB ring-3
    __shared__ float rowpart[8][64];                          // 2 KiB

    const int tid  = threadIdx.x;
    const int wave = tid >> 6;        // 0..7 : cols wave*64..+63
    const int lane = tid & 63;
    const int half = lane >> 5;
    const int nl   = lane & 31;
    const int m0   = blockIdx.x * 64;

    f32x16 acc[2][2];
    #pragma unroll
    for (int mi = 0; mi < 2; ++mi)
        #pragma unroll
        for (int ni = 0; ni < 2; ++ni)
            #pragma unroll
            for (int r = 0; r < 16; ++r) acc[mi][ni][r] = 0.f;

    const int xr = tid >> 3;     // 0..63 (x row)
    const int kp = tid & 7;      // 0..7  (2-elem k-chunk within 16-k stage)
    const float* xb = x + (size_t)(m0 + xr) * D_DIM + kp * 2;

    float2 pxr[2];

    // ---- prologue: issue stages 0 and 1 (px first, then W DMA — order matters
    // for the counted waits), then pack stage 0's x into xs[0].
    asm volatile("global_load_dwordx2 %0, %1, off" : "=v"(pxr[0]) : "v"(xb));
    ASYNC_CP16(Wb2 + tid * 8,        &wsh[0][tid * 8]);
    ASYNC_CP16(Wb2 + tid * 8 + 4096, &wsh[0][tid * 8 + 4096]);
    asm volatile("global_load_dwordx2 %0, %1, off" : "=v"(pxr[1]) : "v"(xb + 16));
    ASYNC_CP16(Wb2 + 8192 + tid * 8,        &wsh[1][tid * 8]);
    ASYNC_CP16(Wb2 + 8192 + tid * 8 + 4096, &wsh[1][tid * 8 + 4096]);
    asm volatile("s_waitcnt vmcnt(5)" ::: "memory");   // px(0) ready
    __builtin_amdgcn_sched_barrier(0);
    {
        unsigned int pk = (unsigned int)f2bf(pxr[0].x) | ((unsigned int)f2bf(pxr[0].y) << 16);
        *(unsigned int*)&xs[0][xr * XLDE + kp * 2] = pk;
    }

    #pragma unroll
    for (int s = 0; s < 32; ++s) {
        // 1. issue stage s+2 (px first, then 2x W DMA)
        if (s + 2 < 32) {
            asm volatile("global_load_dwordx2 %0, %1, off"
                         : "=v"(pxr[s & 1]) : "v"(xb + (s + 2) * 16));
            ASYNC_CP16(Wb2 + (size_t)(s + 2) * 8192 + tid * 8,
                       &wsh[(s + 2) & 3][tid * 8]);
            ASYNC_CP16(Wb2 + (size_t)(s + 2) * 8192 + tid * 8 + 4096,
                       &wsh[(s + 2) & 3][tid * 8 + 4096]);
            // 2. retire {W(s), px(s+1)}; keep W(s+1), px(s+2), W(s+2) in flight
            asm volatile("s_waitcnt vmcnt(5)" ::: "memory");
        } else if (s == 30) {
            asm volatile("s_waitcnt vmcnt(2)" ::: "memory");  // W(30)+px(31) done
        } else {
            asm volatile("s_waitcnt vmcnt(0)" ::: "memory");  // W(31) done
        }
        __builtin_amdgcn_sched_barrier(0);
        // 3. pack px(s+1) into xs ring
        if (s + 1 < 32) {
            float2 p = pxr[(s + 1) & 1];
            unsigned int pk = (unsigned int)f2bf(p.x) | ((unsigned int)f2bf(p.y) << 16);
            *(unsigned int*)&xs[(s + 1) % 3][xr * XLDE + kp * 2] = pk;
        }
        // 4. drain LDS writes, sync
        asm volatile("s_waitcnt lgkmcnt(0)" ::: "memory");
        __builtin_amdgcn_s_barrier();
        __builtin_amdgcn_sched_barrier(0);

        // 5. fragments for stage s (asm ds_read_b128: no hidden vmcnt(0))
        short8v af0, af1, bf0, bf1;
        {
            unsigned a0 = ldsaddr(&xs[s % 3][(nl) * XLDE + half * 8]);
            unsigned a1 = ldsaddr(&xs[s % 3][(32 + nl) * XLDE + half * 8]);
            unsigned b0 = ldsaddr(&wsh[s & 3][(((wave * 2 + 0) * 2 + half) * 32 + nl) * 8]);
            unsigned b1 = ldsaddr(&wsh[s & 3][(((wave * 2 + 1) * 2 + half) * 32 + nl) * 8]);
            asm volatile("ds_read_b128 %0, %1" : "=v"(af0) : "v"(a0) : "memory");
            asm volatile("ds_read_b128 %0, %1" : "=v"(af1) : "v"(a1) : "memory");
            asm volatile("ds_read_b128 %0, %1" : "=v"(bf0) : "v"(b0) : "memory");
            asm volatile("ds_read_b128 %0, %1" : "=v"(bf1) : "v"(b1) : "memory");
        }
        asm volatile("s_waitcnt lgkmcnt(0)" ::: "memory");
        __builtin_amdgcn_sched_barrier(0);

        // 6. MFMA (32x32x16, K=16 per stage)
        acc[0][0] = __builtin_amdgcn_mfma_f32_32x32x16_bf16(af0, bf0, acc[0][0], 0, 0, 0);
        acc[0][1] = __builtin_amdgcn_mfma_f32_32x32x16_bf16(af0, bf1, acc[0][1], 0, 0, 0);
        acc[1][0] = __builtin_amdgcn_mfma_f32_32x32x16_bf16(af1, bf0, acc[1][0], 0, 0, 0);
        acc[1][1] = __builtin_amdgcn_mfma_f32_32x32x16_bf16(af1, bf1, acc[1][1], 0, 0, 0);
    }

    // ---- epilogue 1: ait[m] = sum_e tanh(C[m][e]+bias[e]) * u[e] ----
    // C/D layout: col = lane&31, row = (reg&3) + 8*(reg>>2) + 4*(lane>>5)
    float rowsum[2][16];
    #pragma unroll
    for (int mi = 0; mi < 2; ++mi)
        #pragma unroll
        for (int r = 0; r < 16; ++r) rowsum[mi][r] = 0.f;

    #pragma unroll
    for (int mi = 0; mi < 2; ++mi) {
        #pragma unroll
        for (int ni = 0; ni < 2; ++ni) {
            int col = wave * 64 + ni * 32 + nl;
            float be = bias[col], ue = u[col];
            #pragma unroll
            for (int r = 0; r < 16; ++r)
                rowsum[mi][r] += fast_tanh(acc[mi][ni][r] + be) * ue;
        }
    }
    #pragma unroll
    for (int mi = 0; mi < 2; ++mi)
        #pragma unroll
        for (int r = 0; r < 16; ++r) {
            float v = rowsum[mi][r];
            v += __shfl_xor(v, 1, 64);
            v += __shfl_xor(v, 2, 64);
            v += __shfl_xor(v, 4, 64);
            v += __shfl_xor(v, 8, 64);
            v += __shfl_xor(v, 16, 64);
            rowsum[mi][r] = v;
        }
    if (nl == 0) {
        #pragma unroll
        for (int mi = 0; mi < 2; ++mi)
            #pragma unroll
            for (int r = 0; r < 16; ++r) {
                int row = mi * 32 + (r & 3) + 8 * (r >> 2) + 4 * half;
                rowpart[wave][row] = rowsum[mi][r];
            }
    }
    __syncthreads();   // rowpart complete; wsh/xs dead -> reusable as scratch

    // ---- epilogue 2: e = exp(ait), denom atomic ----
    const int b = m0 / T;                       // batch of this 64-row tile
    float* evals = (float*)&xs[0][0];           // 64 floats, reused LDS
    if (tid < 64) {
        float s = 0.f;
        #pragma unroll
        for (int w = 0; w < 8; ++w) s += rowpart[w][tid];
        float e = __expf(s);
        evals[tid] = e;
        float t = e;
        t += __shfl_xor(t, 1, 64);
        t += __shfl_xor(t, 2, 64);
        t += __shfl_xor(t, 4, 64);
        t += __shfl_xor(t, 8, 64);
        t += __shfl_xor(t, 16, 64);
        t += __shfl_xor(t, 32, 64);
        if (tid == 0) atomicAdd(denom + b, t);
    }
    __syncthreads();   // evals ready

    // ---- epilogue 3: numer[b][d] += sum_r e[r] * x[m0+r][d] ----
    const int dg = tid >> 7;                    // 0..3
    const int d4 = (tid & 127) << 2;            // 0..508
    const float* xp = x + (size_t)m0 * D_DIM + d4;
    float4 pacc = {0.f, 0.f, 0.f, 0.f};
    #pragma unroll 4
    for (int r = dg; r < 64; r += 4) {
        float e = evals[r];
        float4 xv = *(const float4*)(xp + (size_t)r * D_DIM);
        pacc.x += e * xv.x; pacc.y += e * xv.y;
        pacc.z += e * xv.z; pacc.w += e * xv.w;
    }
    float4* ptmp = (float4*)&wsh[0][0];         // 3*128 float4, reused LDS
    if (dg > 0) ptmp[(dg - 1) * 128 + (tid & 127)] = pacc;
    __syncthreads();
    if (dg == 0) {
        float4 o0 = ptmp[tid], o1 = ptmp[128 + tid], o2 = ptmp[256 + tid];
        float* np = numer + (size_t)b * D_DIM + d4;
        atomicAdd(np + 0, pacc.x + o0.x + o1.x + o2.x);
        atomicAdd(np + 1, pacc.y + o0.y + o1.y + o2.y);
        atomicAdd(np + 2, pacc.z + o0.z + o1.z + o2.z);
        atomicAdd(np + 3, pacc.w + o0.w + o1.w + o2.w);
    }
}

// ---- final divide: out[b][d] = numer[b][d] / (denom[b] + eps) ----
__global__ __launch_bounds__(128) void out_div_kernel(
    const float* __restrict__ numer, const float* __restrict__ denom,
    float* __restrict__ out)
{
    const int b = blockIdx.x;
    const int tid = threadIdx.x;
    float inv = 1.0f / (denom[b] + 1e-7f);
    float4 v = *(const float4*)(numer + (size_t)b * D_DIM + tid * 4);
    v.x *= inv; v.y *= inv; v.z *= inv; v.w *= inv;
    *(float4*)(out + (size_t)b * D_DIM + tid * 4) = v;
}

// ---- fp32 fallback GEMM (only if ws < 768 KiB — never observed) ----
__global__ __launch_bounds__(256) void gemm_ait_f32(
    const float* __restrict__ x, const float* __restrict__ W,
    const float* __restrict__ bias, const float* __restrict__ u,
    float* __restrict__ ait)
{
    __shared__ float xsf[64][68];
    __shared__ float wshf[64][132];
    const int tid = threadIdx.x;
    const int tx = tid & 15, ty = tid >> 4;
    const int m0 = blockIdx.x * 64;
    float rowsum[4] = {0.f, 0.f, 0.f, 0.f};
    for (int e0 = 0; e0 < D_DIM; e0 += 128) {
        float acc[4][8];
        #pragma unroll
        for (int i = 0; i < 4; ++i)
            #pragma unroll
            for (int j = 0; j < 8; ++j) acc[i][j] = 0.f;
        for (int kc = 0; kc < D_DIM; kc += 64) {
            #pragma unroll
            for (int i = 0; i < 4; ++i) {
                int idx = tid + i * 256;
                int r = idx >> 4, c = (idx & 15) * 4;
                *(float4*)&xsf[r][c] = *(const float4*)(x + (size_t)(m0 + r) * D_DIM + kc + c);
            }
            #pragma unroll
            for (int i = 0; i < 8; ++i) {
                int idx = tid + i * 256;
                int r = idx >> 5, c = (idx & 31) * 4;
                *(float4*)&wshf[r][c] = *(const float4*)(W + (size_t)(kc + r) * D_DIM + e0 + c);
            }
            __syncthreads();
            #pragma unroll 4
            for (int k = 0; k < 64; ++k) {
                float xv[4];
                #pragma unroll
                for (int i = 0; i < 4; ++i) xv[i] = xsf[ty * 4 + i][k];
                float4 w0 = *(const float4*)&wshf[k][tx * 8];
                float4 w1 = *(const float4*)&wshf[k][tx * 8 + 4];
                #pragma unroll
                for (int i = 0; i < 4; ++i) {
                    acc[i][0] += xv[i] * w0.x; acc[i][1] += xv[i] * w0.y;
                    acc[i][2] += xv[i] * w0.z; acc[i][3] += xv[i] * w0.w;
                    acc[i][4] += xv[i] * w1.x; acc[i][5] += xv[i] * w1.y;
                    acc[i][6] += xv[i] * w1.z; acc[i][7] += xv[i] * w1.w;
                }
            }
            __syncthreads();
        }
        #pragma unroll
        for (int j = 0; j < 8; ++j) {
            int e = e0 + tx * 8 + j;
            float be = bias[e], ue = u[e];
            #pragma unroll
            for (int i = 0; i < 4; ++i) rowsum[i] += tanhf(acc[i][j] + be) * ue;
        }
    }
    float* red = &xsf[0][0];
    #pragma unroll
    for (int i = 0; i < 4; ++i) red[(ty * 4 + i) * 16 + tx] = rowsum[i];
    __syncthreads();
    if (tid < 64) {
        float s = 0.f;
        #pragma unroll
        for (int j = 0; j < 16; ++j) s += red[tid * 16 + j];
        ait[m0 + tid] = s;
    }
}

// ---- softmax over T (fallback path) ----
__global__ __launch_bounds__(256) void softmax_kernel(float* __restrict__ ait, int T)
{
    const int b = blockIdx.x;
    float* p = ait + (size_t)b * T;
    const int tid = threadIdx.x;
    float ev[8];
    float local = 0.f;
    #pragma unroll
    for (int i = 0; i < 8; ++i) {
        ev[i] = expf(p[tid + i * 256]);
        local += ev[i];
    }
    #pragma unroll
    for (int off = 32; off > 0; off >>= 1)
        local += __shfl_down(local, off, 64);
    __shared__ float wsum[4];
    const int wv = tid >> 6, lane = tid & 63;
    if (lane == 0) wsum[wv] = local;
    __syncthreads();
    float total = wsum[0] + wsum[1] + wsum[2] + wsum[3];
    float inv = 1.0f / (total + 1e-7f);
    #pragma unroll
    for (int i = 0; i < 8; ++i) p[tid + i * 256] = ev[i] * inv;
}

// ---- fallback pool (tiny-ws path only) ----
__global__ __launch_bounds__(256) void pool_atomic_kernel(
    const float* __restrict__ x, const float* __restrict__ a,
    float* __restrict__ out, int T)
{
    const int chunks = T >> 8;
    const int b = blockIdx.x / chunks;
    const int c = blockIdx.x % chunks;
    const int tid = threadIdx.x;
    const int th = tid >> 7;
    const int d = (tid & 127) * 4;
    const float* xp = x + ((size_t)b * T + c * 256) * D_DIM + d;
    const float* ap = a + (size_t)b * T + c * 256;
    float4 acc = {0.f, 0.f, 0.f, 0.f};
    #pragma unroll 8
    for (int t = th; t < 256; t += 2) {
        float s = ap[t];
        float4 xv = *(const float4*)(xp + (size_t)t * D_DIM);
        acc.x += xv.x * s; acc.y += xv.y * s;
        acc.z += xv.z * s; acc.w += xv.w * s;
    }
    __shared__ float4 tmp[128];
    if (th == 1) tmp[tid & 127] = acc;
    __syncthreads();
    if (th == 0) {
        float4 o = tmp[tid];
        float* op = out + (size_t)b * D_DIM + tid * 4;
        atomicAdd(op + 0, acc.x + o.x);
        atomicAdd(op + 1, acc.y + o.y);
        atomicAdd(op + 2, acc.z + o.z);
        atomicAdd(op + 3, acc.w + o.w);
    }
}

extern "C" void kernel_launch(void* const* d_in, const int* in_sizes, int n_in,
                              void* d_out, int out_size, void* d_ws, size_t ws_size,
                              hipStream_t stream)
{
    const float* x    = (const float*)d_in[0];
    const float* W    = (const float*)d_in[1];
    const float* bias = (const float*)d_in[2];
    const float* u    = (const float*)d_in[3];
    float* out = (float*)d_out;

    const int Dd = in_sizes[2];          // 512
    const int M  = in_sizes[0] / Dd;     // 65536
    const int B  = out_size / Dd;        // 32
    const int T  = M / B;                // 2048
    const int chunks = T >> 8;           // 8

    const size_t wb_bytes  = (size_t)Dd * Dd * sizeof(unsigned short);   // 512 KiB
    const size_t ait_bytes = (size_t)M * sizeof(float);                  // 256 KiB

    if (ws_size >= wb_bytes + ait_bytes) {
        // [0, 512K): Wb2.  [512K, 576K): numer (B x D).  [576K, +128B): denom.
        unsigned short* Wb2 = (unsigned short*)d_ws;
        float* numer = (float*)((char*)d_ws + wb_bytes);
        float* denom = numer + (size_t)B * Dd;
        const int zero_count = B * Dd + B;   // numer + denom contiguous

        wt_kernel<<<dim3(16), dim3(1024), 0, stream>>>(W, Wb2, numer, zero_count);
        gemm_ait_fused<<<dim3(M / 64), dim3(512), 0, stream>>>(x, Wb2, bias, u,
                                                               numer, denom, T);
        out_div_kernel<<<dim3(B), dim3(128), 0, stream>>>(numer, denom, out);
    } else {
        float* ait = (float*)d_ws;
        gemm_ait_f32<<<dim3(M / 64), dim3(256), 0, stream>>>(x, W, bias, u, ait);
        softmax_kernel<<<dim3(B), dim3(256), 0, stream>>>(ait, T);
        hipMemsetAsync(d_out, 0, (size_t)out_size * sizeof(float), stream);
        pool_atomic_kernel<<<dim3(B * chunks), dim3(256), 0, stream>>>(x, ait, out, T);
    }
}